// Round 9
// baseline (226.356 us; speedup 1.0000x reference)
//
#include <hip/hip_runtime.h>
#include <hip/hip_bf16.h>
#include <math.h>

#define B_ 4
#define F_ 256
#define C_ 19
#define S_ 256
#define N_ 16384
#define M_ 9728
#define MT_ 38           // m-tiles (256 cols each) in pass1
#define P2_BLOCKS (C_ * 16)

typedef __bf16 bf16_t;
typedef bf16_t bf16x8 __attribute__((ext_vector_type(8)));
typedef float floatx4 __attribute__((ext_vector_type(4)));

#define AS1 __attribute__((address_space(1)))
#define AS3 __attribute__((address_space(3)))

// Fragment-order layout (validated r5-r8): element (row, f) lives at
//   ((row>>4)*8 + (f>>5))*512 + ((f>>3)&3)*128 + (row&15)*8 + (f&7)
// fragment (16-row group g, k-step kt) = contiguous 1 KB at (g*8+kt)*512,
// ordered lane*8 with lane=(kchunk<<4)|row.
__device__ inline size_t fragoff(int row, int f) {
    return ((size_t)((row >> 4) * 8 + (f >> 5))) * 512
         + (size_t)((((f >> 3) & 3) * 128) + ((row & 15) * 8) + (f & 7));
}

// ---------------- kernel 1: fused prep + bucketing ----------------
__global__ __launch_bounds__(256) void k_prep(const float* __restrict__ pred,
                                              const float* __restrict__ mem,
                                              const int* __restrict__ labels,
                                              const int* __restrict__ mask,
                                              __hip_bfloat16* __restrict__ A16f,
                                              __hip_bfloat16* __restrict__ B16,
                                              int* __restrict__ ccnt,
                                              int* __restrict__ pix) {
    int bid = blockIdx.x;
    int t = threadIdx.x;
    if (bid < 256) {
        __shared__ float part[4][64];
        __shared__ float invf_s[64];
        __shared__ int hist[C_], base_s[C_], cur[C_];
        int b = bid >> 6, hw0 = (bid & 63) * 64;
        int j = t & 63, q = t >> 6;
        int n0 = b * 4096 + hw0;

        if (t < C_) { hist[t] = 0; cur[t] = 0; }
        int myc = 0, mym = 0;
        if (t < 64) { myc = labels[n0 + t]; mym = mask[n0 + t]; }

        const float* base = pred + ((size_t)b * F_ + q * 64) * 4096 + hw0 + j;
        float v[64];
        float s = 0.f;
        #pragma unroll
        for (int i = 0; i < 64; ++i) {
            float x = base[(size_t)i * 4096];
            v[i] = x;
            s += x * x;
        }
        part[q][j] = s;
        __syncthreads();
        if (t < 64) invf_s[t] = 1.0f / sqrtf(part[0][t] + part[1][t] + part[2][t] + part[3][t]);
        if (t < 64 && mym) atomicAdd(&hist[myc], 1);
        __syncthreads();
        if (t < C_) base_s[t] = atomicAdd(&ccnt[t], hist[t]);
        float invf = invf_s[j];
        #pragma unroll
        for (int c = 0; c < 8; ++c) {
            int f = q * 64 + c * 8;
            __hip_bfloat16 tmp[8];
            #pragma unroll
            for (int u = 0; u < 8; ++u) tmp[u] = __float2bfloat16(v[c * 8 + u] * invf);
            *(float4*)&A16f[fragoff(n0 + j, f)] = *(float4*)tmp;
        }
        __syncthreads();
        if (t < 64 && mym) {
            int o = atomicAdd(&cur[myc], 1);
            pix[myc * N_ + base_s[myc] + o] = n0 + t;
        }
    } else {
        int row  = (bid - 256) * 4 + (t >> 6);
        int lane = t & 63;
        float4 a = ((const float4*)(mem + (size_t)row * F_))[lane];
        float s = a.x*a.x + a.y*a.y + a.z*a.z + a.w*a.w;
        #pragma unroll
        for (int off = 32; off; off >>= 1) s += __shfl_xor(s, off, 64);
        float invm = 1.0f / sqrtf(s);
        __hip_bfloat16 tmp[4];
        tmp[0] = __float2bfloat16(a.x * invm);
        tmp[1] = __float2bfloat16(a.y * invm);
        tmp[2] = __float2bfloat16(a.z * invm);
        tmp[3] = __float2bfloat16(a.w * invm);
        *(float2*)&B16[fragoff(row, lane * 4)] = *(float2*)tmp;
    }
}

// ---------------- kernel 2: pass-1 row-sum GEMM, 64n x 256m blocks ----------------
// grid 9728 1-D, 256 thr = 4 waves; wave w = 64n x 64m (acc 4x4).  XCD-aware
// decode: blocks with the same m-tile cluster on one XCD (B-tile L2 reuse).
// A panel (64 rows x 256 K = 32 KB, contiguous in frag-order A16f) staged once
// via global_load_lds; zero barriers in the K-loop; B register-direct.
// Per-block row sums combined in LDS -> one totpart slot per m-tile.
__global__ __launch_bounds__(256, 3) void k_pass1(const __hip_bfloat16* __restrict__ A16f,
                                                  const __hip_bfloat16* __restrict__ B16,
                                                  float* __restrict__ totpart) {
    __shared__ __hip_bfloat16 As[64 * 256];   // 32 KB
    __shared__ float totals_s[4][64];
    int t = threadIdx.x, w = t >> 6, lane = t & 63;
    int bid = blockIdx.x;
    int xcd = bid & 7, j = bid >> 3;
    int mt = j >> 5;                       // 0..37
    int n0 = (((j & 31) << 3) | xcd) * 64; // 0..16320
    int m0 = mt * 256;

    // stage A panel (contiguous 32 KB starting at n0*256)
    {
        const __hip_bfloat16* src = A16f + ((size_t)n0 << 8) + w * 4096 + lane * 8;
        __hip_bfloat16* dst = &As[w * 4096];
        #pragma unroll
        for (int i = 0; i < 8; ++i)
            __builtin_amdgcn_global_load_lds((const AS1 unsigned int*)(src + i * 512),
                                             (AS3 unsigned int*)(dst + i * 512), 16, 0, 0);
    }
    __syncthreads();

    floatx4 acc[4][4];
    #pragma unroll
    for (int i = 0; i < 4; ++i)
        #pragma unroll
        for (int j2 = 0; j2 < 4; ++j2) acc[i][j2] = (floatx4){0.f, 0.f, 0.f, 0.f};

    const bf16x8* Bp = (const bf16x8*)B16 + ((size_t)((m0 >> 4) + w * 4) * 8) * 64 + lane;

    #pragma unroll
    for (int kt = 0; kt < 8; ++kt) {
        bf16x8 af[4], bfr[4];
        #pragma unroll
        for (int ni = 0; ni < 4; ++ni)
            af[ni] = *(const bf16x8*)&As[(ni * 8 + kt) * 512 + lane * 8];
        #pragma unroll
        for (int mi = 0; mi < 4; ++mi)
            bfr[mi] = Bp[(size_t)(mi * 8 + kt) * 64];
        #pragma unroll
        for (int ni = 0; ni < 4; ++ni)
            #pragma unroll
            for (int mi = 0; mi < 4; ++mi)
                acc[ni][mi] = __builtin_amdgcn_mfma_f32_16x16x32_bf16(af[ni], bfr[mi], acc[ni][mi], 0, 0, 0);
    }

    // epilogue: E = exp(2*cos) -> per-row sums -> LDS combine -> one totpart slot
    float racc[4][4];
    #pragma unroll
    for (int ni = 0; ni < 4; ++ni)
        #pragma unroll
        for (int r = 0; r < 4; ++r) racc[ni][r] = 0.f;
    #pragma unroll
    for (int ni = 0; ni < 4; ++ni)
        #pragma unroll
        for (int mi = 0; mi < 4; ++mi)
            #pragma unroll
            for (int r = 0; r < 4; ++r)
                racc[ni][r] += __expf(2.0f * acc[ni][mi][r]);

    int colL = lane & 15, rgrp = (lane >> 4) * 4;
    #pragma unroll
    for (int ni = 0; ni < 4; ++ni)
        #pragma unroll
        for (int r = 0; r < 4; ++r) {
            float s = racc[ni][r];
            s += __shfl_xor(s, 1, 64);
            s += __shfl_xor(s, 2, 64);
            s += __shfl_xor(s, 4, 64);
            s += __shfl_xor(s, 8, 64);
            if (colL == 0) totals_s[w][ni * 16 + rgrp + r] = s;
        }
    __syncthreads();
    if (t < 64)
        totpart[(size_t)mt * N_ + n0 + t] =
            totals_s[0][t] + totals_s[1][t] + totals_s[2][t] + totals_s[3][t];
}

// ---------------- kernel 3: pass-2 own-class recompute + terms + final ----------------
// grid (19, 16), 512 thr = 8 waves; block = (class c, 64-pixel tile).  Computes
// total[] inline from the 38 totpart slots; per-block class partial -> atomic
// class_sum; completion counter -> last block writes the final loss.
__global__ __launch_bounds__(512) void k_pass2(const __hip_bfloat16* __restrict__ A16f,
                                               const __hip_bfloat16* __restrict__ B16,
                                               const int* __restrict__ ccnt,
                                               const int* __restrict__ pix,
                                               const float* __restrict__ totpart,
                                               const int* __restrict__ wmem,
                                               float* __restrict__ class_sum,
                                               int* __restrict__ done,
                                               float* __restrict__ out) {
    __shared__ __hip_bfloat16 As[64 * 256];   // 32 KB, fragment order
    __shared__ int pidx_s[64];
    __shared__ float tot_s[64];
    __shared__ int wm_s[64];
    __shared__ float bsum_s[8][64];
    __shared__ float wsum_s[8][64];
    __shared__ float down_s[64];
    __shared__ float term_s[64];

    int c = blockIdx.x, tile = blockIdx.y;
    int cnt = ccnt[c];
    int t = threadIdx.x, ws = t >> 6, lane = t & 63;

    if (tile * 64 >= cnt) {                    // empty tile: still hit the counter
        if (t == 0) {
            __threadfence();
            int old = atomicAdd(done, 1);
            if (old == P2_BLOCKS - 1) {
                float loss = 0.f, kc = 0.f;
                for (int cc = 0; cc < C_; ++cc) {
                    int cn = ccnt[cc];
                    float sc = atomicAdd(&class_sum[cc], 0.f);
                    if (cn > 0) { loss += sc / ((float)cn * (float)S_); kc += 1.f; }
                }
                out[0] = loss / fmaxf(kc, 1.f);
            }
        }
        return;
    }

    if (t < 64) {
        int i = tile * 64 + t;
        int p = pix[c * N_ + (i < cnt ? i : 0)];
        pidx_s[t] = p;
        wm_s[t]   = wmem[p];
    }
    __syncthreads();

    // inline total: 8 threads per pixel sum the 38 partial slots
    {
        int px = t >> 3, g = t & 7;
        int p = pidx_s[px];
        float s = 0.f;
        for (int i = g; i < MT_; i += 8) s += totpart[(size_t)i * N_ + p];
        s += __shfl_xor(s, 1, 64);
        s += __shfl_xor(s, 2, 64);
        s += __shfl_xor(s, 4, 64);
        if (g == 0) tot_s[px] = s;
    }

    // gather A rows (frag-order chunks) into LDS fragment order
    #pragma unroll
    for (int s2 = 0; s2 < 4; ++s2) {
        int g = t + 512 * s2;          // 0..2047: 64 rows x 32 16B-chunks
        int row = g >> 5, f = (g & 31) * 8;
        float4 v = *(const float4*)&A16f[fragoff(pidx_s[row], f)];
        *(float4*)&As[fragoff(row, f)] = v;
    }
    __syncthreads();

    floatx4 acc[4][4];
    #pragma unroll
    for (int i = 0; i < 4; ++i)
        #pragma unroll
        for (int j = 0; j < 4; ++j) acc[i][j] = (floatx4){0.f, 0.f, 0.f, 0.f};

    const bf16x8* Bp = (const bf16x8*)B16 + ((size_t)(c * 32 + ws * 4) * 8) * 64 + lane;
    #pragma unroll
    for (int kt = 0; kt < 8; ++kt) {
        bf16x8 af[4], bfr[4];
        #pragma unroll
        for (int ni = 0; ni < 4; ++ni)
            af[ni] = *(const bf16x8*)&As[(ni * 8 + kt) * 512 + lane * 8];
        #pragma unroll
        for (int mi = 0; mi < 4; ++mi) bfr[mi] = Bp[(size_t)(mi * 8 + kt) * 64];
        #pragma unroll
        for (int ni = 0; ni < 4; ++ni)
            #pragma unroll
            for (int mi = 0; mi < 4; ++mi)
                acc[ni][mi] = __builtin_amdgcn_mfma_f32_16x16x32_bf16(af[ni], bfr[mi], acc[ni][mi], 0, 0, 0);
    }

    int colL = lane & 15, rgrp = (lane >> 4) * 4;
    float Ev[4][4][4];
    #pragma unroll
    for (int ni = 0; ni < 4; ++ni)
        #pragma unroll
        for (int mi = 0; mi < 4; ++mi)
            #pragma unroll
            for (int r = 0; r < 4; ++r)
                Ev[ni][mi][r] = __expf(2.0f * acc[ni][mi][r]);

    #pragma unroll
    for (int ni = 0; ni < 4; ++ni)
        #pragma unroll
        for (int r = 0; r < 4; ++r) {
            float s = Ev[ni][0][r] + Ev[ni][1][r] + Ev[ni][2][r] + Ev[ni][3][r];
            s += __shfl_xor(s, 1, 64);
            s += __shfl_xor(s, 2, 64);
            s += __shfl_xor(s, 4, 64);
            s += __shfl_xor(s, 8, 64);
            if (colL == 0) bsum_s[ws][ni * 16 + rgrp + r] = s;
        }
    __syncthreads();
    if (t < 64) {
        float bs = 0.f;
        #pragma unroll
        for (int w2 = 0; w2 < 8; ++w2) bs += bsum_s[w2][t];
        down_s[t] = tot_s[t] - bs;
    }
    __syncthreads();

    #pragma unroll
    for (int ni = 0; ni < 4; ++ni)
        #pragma unroll
        for (int r = 0; r < 4; ++r) {
            int row = ni * 16 + rgrp + r;
            bool sel = (wm_s[row] == 1) ? (ws < 4) : (ws >= 4);
            float tt = 0.f;
            if (sel) {
                float dwn = down_s[row];
                #pragma unroll
                for (int mi = 0; mi < 4; ++mi) {
                    float pv = Ev[ni][mi][r];
                    tt += -logf(pv / (pv + dwn + 1e-12f) + 1e-12f);
                }
            }
            tt += __shfl_xor(tt, 1, 64);
            tt += __shfl_xor(tt, 2, 64);
            tt += __shfl_xor(tt, 4, 64);
            tt += __shfl_xor(tt, 8, 64);
            if (colL == 0) wsum_s[ws][row] = tt;
        }
    __syncthreads();
    if (t < 64) {
        int i = tile * 64 + t;
        float s = 0.f;
        if (i < cnt) {
            #pragma unroll
            for (int w2 = 0; w2 < 8; ++w2) s += wsum_s[w2][t];
        }
        term_s[t] = s;
    }
    __syncthreads();
    if (t < 64) {                                // wave 0: block reduce + atomics
        float s = term_s[t];
        #pragma unroll
        for (int off = 1; off < 64; off <<= 1) s += __shfl_xor(s, off, 64);
        if (t == 0) {
            atomicAdd(&class_sum[c], s);
            __threadfence();
            int old = atomicAdd(done, 1);
            if (old == P2_BLOCKS - 1) {
                float loss = 0.f, kc = 0.f;
                for (int cc = 0; cc < C_; ++cc) {
                    int cn = ccnt[cc];
                    float sc = atomicAdd(&class_sum[cc], 0.f);
                    if (cn > 0) { loss += sc / ((float)cn * (float)S_); kc += 1.f; }
                }
                out[0] = loss / fmaxf(kc, 1.f);
            }
        }
    }
}

extern "C" void kernel_launch(void* const* d_in, const int* in_sizes, int n_in,
                              void* d_out, int out_size, void* d_ws, size_t ws_size,
                              hipStream_t stream) {
    const float* mem    = (const float*)d_in[0];
    const float* pred   = (const float*)d_in[1];
    const int*   labels = (const int*)  d_in[2];
    const int*   mask   = (const int*)  d_in[3];
    const int*   wmem   = (const int*)  d_in[4];
    float* out = (float*)d_out;

    float* ws = (float*)d_ws;
    float* totpart   = ws;                            // 38*N_ = 622,592 floats
    int*   ccnt      = (int*)(ws + 622592);           // 19 ints   (memset 0)
    float* class_sum = ws + 622611;                   // 19 floats (memset 0)
    int*   done      = (int*)(ws + 622630);           // 1 int     (memset 0)
    int*   pix       = (int*)(ws + 622640);           // 19*N_ ints
    __hip_bfloat16* A16f = (__hip_bfloat16*)(ws + 933936);    // 8 MB (frag order)
    __hip_bfloat16* B16  = (__hip_bfloat16*)(ws + 3031088);   // 4.86 MB (frag order)

    hipMemsetAsync(ccnt, 0, 39 * sizeof(int), stream);   // ccnt + class_sum + done

    k_prep<<<256 + M_ / 4, 256, 0, stream>>>(pred, mem, labels, mask,
                                             A16f, B16, ccnt, pix);

    k_pass1<<<MT_ * 256, 256, 0, stream>>>(A16f, B16, totpart);

    dim3 g2(C_, 16);
    k_pass2<<<g2, 512, 0, stream>>>(A16f, B16, ccnt, pix, totpart, wmem,
                                    class_sum, done, out);
}

// Round 10
// 211.384 us; speedup vs baseline: 1.0708x; 1.0708x over previous
//
#include <hip/hip_runtime.h>
#include <hip/hip_bf16.h>
#include <math.h>

#define B_ 4
#define F_ 256
#define C_ 19
#define S_ 256
#define N_ 16384
#define M_ 9728
#define MT_ 38           // m-tiles (256 cols each) in pass1
#define GEMM_BLKS 4864   // 38 mt * 128 nt
#define P2_BLOCKS (C_ * 16)

typedef __bf16 bf16_t;
typedef bf16_t bf16x8 __attribute__((ext_vector_type(8)));
typedef float floatx4 __attribute__((ext_vector_type(4)));

#define AS1 __attribute__((address_space(1)))
#define AS3 __attribute__((address_space(3)))

// Fragment-order layout (validated r5-r9): element (row, f) lives at
//   ((row>>4)*8 + (f>>5))*512 + ((f>>3)&3)*128 + (row&15)*8 + (f&7)
// fragment (16-row group g, k-step kt) = contiguous 1 KB at (g*8+kt)*512,
// ordered lane*8 with lane=(kchunk<<4)|row.
__device__ inline size_t fragoff(int row, int f) {
    return ((size_t)((row >> 4) * 8 + (f >> 5))) * 512
         + (size_t)((((f >> 3) & 3) * 128) + ((row & 15) * 8) + (f & 7));
}

// ---------------- kernel 1: prep (pure convert; block 0 zeroes control) ----------
__global__ __launch_bounds__(256) void k_prep(const float* __restrict__ pred,
                                              const float* __restrict__ mem,
                                              __hip_bfloat16* __restrict__ A16f,
                                              __hip_bfloat16* __restrict__ B16,
                                              int* __restrict__ ctrl) {
    int bid = blockIdx.x;
    int t = threadIdx.x;
    if (bid < 256) {
        __shared__ float part[4][64];
        __shared__ float invf_s[64];
        if (bid == 0 && t < 40) ctrl[t] = 0;      // ccnt[19]+class_sum[19]+done+pad
        int b = bid >> 6, hw0 = (bid & 63) * 64;
        int j = t & 63, q = t >> 6;
        int n0 = b * 4096 + hw0;

        const float* base = pred + ((size_t)b * F_ + q * 64) * 4096 + hw0 + j;
        float v[64];
        float s = 0.f;
        #pragma unroll
        for (int i = 0; i < 64; ++i) {
            float x = base[(size_t)i * 4096];
            v[i] = x;
            s += x * x;
        }
        part[q][j] = s;
        __syncthreads();
        if (t < 64) invf_s[t] = 1.0f / sqrtf(part[0][t] + part[1][t] + part[2][t] + part[3][t]);
        __syncthreads();
        float invf = invf_s[j];
        #pragma unroll
        for (int c = 0; c < 8; ++c) {
            int f = q * 64 + c * 8;
            __hip_bfloat16 tmp[8];
            #pragma unroll
            for (int u = 0; u < 8; ++u) tmp[u] = __float2bfloat16(v[c * 8 + u] * invf);
            *(float4*)&A16f[fragoff(n0 + j, f)] = *(float4*)tmp;
        }
    } else {
        int row  = (bid - 256) * 4 + (t >> 6);
        int lane = t & 63;
        float4 a = ((const float4*)(mem + (size_t)row * F_))[lane];
        float s = a.x*a.x + a.y*a.y + a.z*a.z + a.w*a.w;
        #pragma unroll
        for (int off = 32; off; off >>= 1) s += __shfl_xor(s, off, 64);
        float invm = 1.0f / sqrtf(s);
        __hip_bfloat16 tmp[4];
        tmp[0] = __float2bfloat16(a.x * invm);
        tmp[1] = __float2bfloat16(a.y * invm);
        tmp[2] = __float2bfloat16(a.z * invm);
        tmp[3] = __float2bfloat16(a.w * invm);
        *(float2*)&B16[fragoff(row, lane * 4)] = *(float2*)tmp;
    }
}

// ---------------- kernel 2: pass-1 GEMM 128n x 256m, 8 waves of 64x64 ----------
// blocks [0, 4864): GEMM.  XCD-aware decode clusters same-mt blocks per XCD.
// A panel (128 rows = 64 KB, contiguous in frag-order A16f) staged once via
// global_load_lds; zero-barrier K-loop; B register-direct (pair-shared -> L1).
// blocks [4864, 4864+64): bucketing of 256 pixels each (ccnt zeroed by prep).
__global__ __launch_bounds__(512, 4) void k_pass1(const __hip_bfloat16* __restrict__ A16f,
                                                  const __hip_bfloat16* __restrict__ B16,
                                                  const int* __restrict__ labels,
                                                  const int* __restrict__ mask,
                                                  float* __restrict__ totpart,
                                                  int* __restrict__ ccnt,
                                                  int* __restrict__ pix) {
    int bid = blockIdx.x;
    int t = threadIdx.x;
    if (bid >= GEMM_BLKS) {                      // ---- bucketing blocks
        __shared__ int hist[C_], base_s[C_], cur[C_];
        int n0 = (bid - GEMM_BLKS) * 256;
        if (t < C_) { hist[t] = 0; cur[t] = 0; }
        __syncthreads();
        int myc = 0, mym = 0;
        if (t < 256) { myc = labels[n0 + t]; mym = mask[n0 + t]; }
        if (t < 256 && mym) atomicAdd(&hist[myc], 1);
        __syncthreads();
        if (t < C_) base_s[t] = atomicAdd(&ccnt[t], hist[t]);
        __syncthreads();
        if (t < 256 && mym) {
            int o = atomicAdd(&cur[myc], 1);
            pix[myc * N_ + base_s[myc] + o] = n0 + t;
        }
        return;
    }

    __shared__ __hip_bfloat16 As[128 * 256];     // 64 KB
    __shared__ float totals_s[4][128];
    int w = t >> 6, lane = t & 63;
    int xcd = bid & 7, j = bid >> 3;
    int mt = j >> 4;                             // 0..37  (608/16)
    int nt = ((j & 15) << 3) | xcd;              // 0..127
    int n0 = nt * 128, m0 = mt * 256;
    int nh = w & 1, mq = w >> 1;

    // stage A panel: 64 KB contiguous, wave w does [w*4096, w*4096+4096) elems
    {
        const __hip_bfloat16* src = A16f + ((size_t)n0 << 8) + w * 4096 + lane * 8;
        __hip_bfloat16* dst = &As[w * 4096];
        #pragma unroll
        for (int i = 0; i < 8; ++i)
            __builtin_amdgcn_global_load_lds((const AS1 unsigned int*)(src + i * 512),
                                             (AS3 unsigned int*)(dst + i * 512), 16, 0, 0);
    }
    __syncthreads();

    floatx4 acc[4][4];
    #pragma unroll
    for (int i = 0; i < 4; ++i)
        #pragma unroll
        for (int j2 = 0; j2 < 4; ++j2) acc[i][j2] = (floatx4){0.f, 0.f, 0.f, 0.f};

    const bf16x8* Bp = (const bf16x8*)B16 + ((size_t)((m0 >> 4) + mq * 4) * 8) * 64 + lane;

    #pragma unroll
    for (int kt = 0; kt < 8; ++kt) {
        bf16x8 af[4], bfr[4];
        #pragma unroll
        for (int ni = 0; ni < 4; ++ni)
            af[ni] = *(const bf16x8*)&As[((nh * 4 + ni) * 8 + kt) * 512 + lane * 8];
        #pragma unroll
        for (int mi = 0; mi < 4; ++mi)
            bfr[mi] = Bp[(size_t)(mi * 8 + kt) * 64];
        #pragma unroll
        for (int ni = 0; ni < 4; ++ni)
            #pragma unroll
            for (int mi = 0; mi < 4; ++mi)
                acc[ni][mi] = __builtin_amdgcn_mfma_f32_16x16x32_bf16(af[ni], bfr[mi], acc[ni][mi], 0, 0, 0);
    }

    // epilogue: E = exp(2*cos) -> wave row-sums -> LDS combine over 4 m-quarters
    float racc[4][4];
    #pragma unroll
    for (int ni = 0; ni < 4; ++ni)
        #pragma unroll
        for (int r = 0; r < 4; ++r) racc[ni][r] = 0.f;
    #pragma unroll
    for (int ni = 0; ni < 4; ++ni)
        #pragma unroll
        for (int mi = 0; mi < 4; ++mi)
            #pragma unroll
            for (int r = 0; r < 4; ++r)
                racc[ni][r] += __expf(2.0f * acc[ni][mi][r]);

    int colL = lane & 15, rgrp = (lane >> 4) * 4;
    #pragma unroll
    for (int ni = 0; ni < 4; ++ni)
        #pragma unroll
        for (int r = 0; r < 4; ++r) {
            float s = racc[ni][r];
            s += __shfl_xor(s, 1, 64);
            s += __shfl_xor(s, 2, 64);
            s += __shfl_xor(s, 4, 64);
            s += __shfl_xor(s, 8, 64);
            if (colL == 0) {
                int row = nh * 64 + ni * 16 + rgrp + r;
                if (mq == 0) totals_s[0][row] = s; else totals_s[mq][row] = s;
            }
        }
    __syncthreads();
    if (t < 128)
        totpart[(size_t)mt * N_ + n0 + t] =
            totals_s[0][t] + totals_s[1][t] + totals_s[2][t] + totals_s[3][t];
}

// ---------------- kernel 3: pass-2 own-class recompute + terms + final ----------------
__global__ __launch_bounds__(512) void k_pass2(const __hip_bfloat16* __restrict__ A16f,
                                               const __hip_bfloat16* __restrict__ B16,
                                               const int* __restrict__ ccnt,
                                               const int* __restrict__ pix,
                                               const float* __restrict__ totpart,
                                               const int* __restrict__ wmem,
                                               float* __restrict__ class_sum,
                                               int* __restrict__ done,
                                               float* __restrict__ out) {
    __shared__ __hip_bfloat16 As[64 * 256];   // 32 KB, fragment order
    __shared__ int pidx_s[64];
    __shared__ float tot_s[64];
    __shared__ int wm_s[64];
    __shared__ float bsum_s[8][64];
    __shared__ float wsum_s[8][64];
    __shared__ float down_s[64];
    __shared__ float term_s[64];

    int c = blockIdx.x, tile = blockIdx.y;
    int cnt = ccnt[c];
    int t = threadIdx.x, ws = t >> 6, lane = t & 63;

    if (tile * 64 >= cnt) {                    // empty tile: still hit the counter
        if (t == 0) {
            __threadfence();
            int old = atomicAdd(done, 1);
            if (old == P2_BLOCKS - 1) {
                float loss = 0.f, kc = 0.f;
                for (int cc = 0; cc < C_; ++cc) {
                    int cn = ccnt[cc];
                    float sc = atomicAdd(&class_sum[cc], 0.f);
                    if (cn > 0) { loss += sc / ((float)cn * (float)S_); kc += 1.f; }
                }
                out[0] = loss / fmaxf(kc, 1.f);
            }
        }
        return;
    }

    if (t < 64) {
        int i = tile * 64 + t;
        int p = pix[c * N_ + (i < cnt ? i : 0)];
        pidx_s[t] = p;
        wm_s[t]   = wmem[p];
    }
    __syncthreads();

    // inline total: 8 threads per pixel sum the 38 partial slots
    {
        int px = t >> 3, g = t & 7;
        int p = pidx_s[px];
        float s = 0.f;
        for (int i = g; i < MT_; i += 8) s += totpart[(size_t)i * N_ + p];
        s += __shfl_xor(s, 1, 64);
        s += __shfl_xor(s, 2, 64);
        s += __shfl_xor(s, 4, 64);
        if (g == 0) tot_s[px] = s;
    }

    // gather A rows (frag-order chunks) into LDS fragment order
    #pragma unroll
    for (int s2 = 0; s2 < 4; ++s2) {
        int g = t + 512 * s2;          // 0..2047: 64 rows x 32 16B-chunks
        int row = g >> 5, f = (g & 31) * 8;
        float4 v = *(const float4*)&A16f[fragoff(pidx_s[row], f)];
        *(float4*)&As[fragoff(row, f)] = v;
    }
    __syncthreads();

    floatx4 acc[4][4];
    #pragma unroll
    for (int i = 0; i < 4; ++i)
        #pragma unroll
        for (int j = 0; j < 4; ++j) acc[i][j] = (floatx4){0.f, 0.f, 0.f, 0.f};

    const bf16x8* Bp = (const bf16x8*)B16 + ((size_t)(c * 32 + ws * 4) * 8) * 64 + lane;
    #pragma unroll
    for (int kt = 0; kt < 8; ++kt) {
        bf16x8 af[4], bfr[4];
        #pragma unroll
        for (int ni = 0; ni < 4; ++ni)
            af[ni] = *(const bf16x8*)&As[(ni * 8 + kt) * 512 + lane * 8];
        #pragma unroll
        for (int mi = 0; mi < 4; ++mi) bfr[mi] = Bp[(size_t)(mi * 8 + kt) * 64];
        #pragma unroll
        for (int ni = 0; ni < 4; ++ni)
            #pragma unroll
            for (int mi = 0; mi < 4; ++mi)
                acc[ni][mi] = __builtin_amdgcn_mfma_f32_16x16x32_bf16(af[ni], bfr[mi], acc[ni][mi], 0, 0, 0);
    }

    int colL = lane & 15, rgrp = (lane >> 4) * 4;
    float Ev[4][4][4];
    #pragma unroll
    for (int ni = 0; ni < 4; ++ni)
        #pragma unroll
        for (int mi = 0; mi < 4; ++mi)
            #pragma unroll
            for (int r = 0; r < 4; ++r)
                Ev[ni][mi][r] = __expf(2.0f * acc[ni][mi][r]);

    #pragma unroll
    for (int ni = 0; ni < 4; ++ni)
        #pragma unroll
        for (int r = 0; r < 4; ++r) {
            float s = Ev[ni][0][r] + Ev[ni][1][r] + Ev[ni][2][r] + Ev[ni][3][r];
            s += __shfl_xor(s, 1, 64);
            s += __shfl_xor(s, 2, 64);
            s += __shfl_xor(s, 4, 64);
            s += __shfl_xor(s, 8, 64);
            if (colL == 0) bsum_s[ws][ni * 16 + rgrp + r] = s;
        }
    __syncthreads();
    if (t < 64) {
        float bs = 0.f;
        #pragma unroll
        for (int w2 = 0; w2 < 8; ++w2) bs += bsum_s[w2][t];
        down_s[t] = tot_s[t] - bs;
    }
    __syncthreads();

    #pragma unroll
    for (int ni = 0; ni < 4; ++ni)
        #pragma unroll
        for (int r = 0; r < 4; ++r) {
            int row = ni * 16 + rgrp + r;
            bool sel = (wm_s[row] == 1) ? (ws < 4) : (ws >= 4);
            float tt = 0.f;
            if (sel) {
                float dwn = down_s[row];
                #pragma unroll
                for (int mi = 0; mi < 4; ++mi) {
                    float pv = Ev[ni][mi][r];
                    tt += -logf(pv / (pv + dwn + 1e-12f) + 1e-12f);
                }
            }
            tt += __shfl_xor(tt, 1, 64);
            tt += __shfl_xor(tt, 2, 64);
            tt += __shfl_xor(tt, 4, 64);
            tt += __shfl_xor(tt, 8, 64);
            if (colL == 0) wsum_s[ws][row] = tt;
        }
    __syncthreads();
    if (t < 64) {
        int i = tile * 64 + t;
        float s = 0.f;
        if (i < cnt) {
            #pragma unroll
            for (int w2 = 0; w2 < 8; ++w2) s += wsum_s[w2][t];
        }
        term_s[t] = s;
    }
    __syncthreads();
    if (t < 64) {
        float s = term_s[t];
        #pragma unroll
        for (int off = 1; off < 64; off <<= 1) s += __shfl_xor(s, off, 64);
        if (t == 0) {
            atomicAdd(&class_sum[c], s);
            __threadfence();
            int old = atomicAdd(done, 1);
            if (old == P2_BLOCKS - 1) {
                float loss = 0.f, kc = 0.f;
                for (int cc = 0; cc < C_; ++cc) {
                    int cn = ccnt[cc];
                    float sc = atomicAdd(&class_sum[cc], 0.f);
                    if (cn > 0) { loss += sc / ((float)cn * (float)S_); kc += 1.f; }
                }
                out[0] = loss / fmaxf(kc, 1.f);
            }
        }
    }
}

extern "C" void kernel_launch(void* const* d_in, const int* in_sizes, int n_in,
                              void* d_out, int out_size, void* d_ws, size_t ws_size,
                              hipStream_t stream) {
    const float* mem    = (const float*)d_in[0];
    const float* pred   = (const float*)d_in[1];
    const int*   labels = (const int*)  d_in[2];
    const int*   mask   = (const int*)  d_in[3];
    const int*   wmem   = (const int*)  d_in[4];
    float* out = (float*)d_out;

    float* ws = (float*)d_ws;
    float* totpart   = ws;                            // 38*N_ = 622,592 floats
    int*   ctrl      = (int*)(ws + 622592);           // 40 words: ccnt|class_sum|done
    int*   ccnt      = ctrl;                          // 19
    float* class_sum = (float*)(ctrl + 19);           // 19
    int*   done      = ctrl + 38;                     // 1
    int*   pix       = (int*)(ws + 622640);           // 19*N_ ints
    __hip_bfloat16* A16f = (__hip_bfloat16*)(ws + 933936);    // 8 MB (frag order)
    __hip_bfloat16* B16  = (__hip_bfloat16*)(ws + 3031088);   // 4.86 MB (frag order)

    k_prep<<<256 + M_ / 4, 256, 0, stream>>>(pred, mem, A16f, B16, ctrl);

    k_pass1<<<GEMM_BLKS + 64, 512, 0, stream>>>(A16f, B16, labels, mask,
                                                totpart, ccnt, pix);

    dim3 g2(C_, 16);
    k_pass2<<<g2, 512, 0, stream>>>(A16f, B16, ccnt, pix, totpart, wmem,
                                    class_sum, done, out);
}